// Round 6
// baseline (282223.877 us; speedup 1.0000x reference)
//
#include <hip/hip_runtime.h>
#include <math.h>

#define DIM 128
#define KC 1024
#define NITER 10
#define BM 64
#define BN 64

// ---- numpy-pairwise sum of squares (n=128 path), bit-exact clone ----
// temp p_i = fl(x_i*x_i)  (separate rounding, NO fma)
// r[j] = p[j]; for blk=1..15: r[j] += p[blk*8+j]
// res = ((r0+r1)+(r2+r3)) + ((r4+r5)+(r6+r7))
__global__ void sq_np_kernel(const float* __restrict__ v, float* __restrict__ out, int rows) {
    int i = blockIdx.x * blockDim.x + threadIdx.x;
    if (i >= rows) return;
    const float4* row = (const float4*)(v + (size_t)i * DIM);
    float r[8];
    {
        float4 a = row[0], b = row[1];
        r[0] = __fmul_rn(a.x, a.x); r[1] = __fmul_rn(a.y, a.y);
        r[2] = __fmul_rn(a.z, a.z); r[3] = __fmul_rn(a.w, a.w);
        r[4] = __fmul_rn(b.x, b.x); r[5] = __fmul_rn(b.y, b.y);
        r[6] = __fmul_rn(b.z, b.z); r[7] = __fmul_rn(b.w, b.w);
    }
    #pragma unroll
    for (int blk = 1; blk < 16; blk++) {
        float4 a = row[blk * 2], b = row[blk * 2 + 1];
        r[0] = __fadd_rn(r[0], __fmul_rn(a.x, a.x));
        r[1] = __fadd_rn(r[1], __fmul_rn(a.y, a.y));
        r[2] = __fadd_rn(r[2], __fmul_rn(a.z, a.z));
        r[3] = __fadd_rn(r[3], __fmul_rn(a.w, a.w));
        r[4] = __fadd_rn(r[4], __fmul_rn(b.x, b.x));
        r[5] = __fadd_rn(r[5], __fmul_rn(b.y, b.y));
        r[6] = __fadd_rn(r[6], __fmul_rn(b.z, b.z));
        r[7] = __fadd_rn(r[7], __fmul_rn(b.w, b.w));
    }
    out[i] = __fadd_rn(__fadd_rn(__fadd_rn(r[0], r[1]), __fadd_rn(r[2], r[3])),
                       __fadd_rn(__fadd_rn(r[4], r[5]), __fadd_rn(r[6], r[7])));
}

// ---- assign: fp32, sgemm-style sequential-fma dot, d=(xsq-2dot)+csq ----
__global__ __launch_bounds__(256) void assign_kernel(
    const float* __restrict__ x, const float* __restrict__ cent,
    const float* __restrict__ xsq, const float* __restrict__ csq,
    int* __restrict__ cl)
{
    __shared__ float4 xs[BM * 32];
    __shared__ float4 cs[BN * 32];
    const int tid = threadIdx.x;
    const int bm = blockIdx.x * BM;

    const float4* xg = (const float4*)x + (size_t)bm * 32;
    #pragma unroll
    for (int p = 0; p < 8; p++) {
        int id = tid + p * 256;
        int r = id >> 5, c4 = id & 31;
        xs[r * 32 + (c4 ^ ((r >> 2) & 7))] = xg[id];
    }

    const int ty = tid >> 4, tx = tid & 15;
    float best[4];
    int bidx[4];
    float xq[4];
    #pragma unroll
    for (int i = 0; i < 4; i++) {
        best[i] = INFINITY; bidx[i] = 0;
        xq[i] = xsq[bm + ty * 4 + i];
    }

    for (int kt = 0; kt < KC / BN; kt++) {
        __syncthreads();
        const float4* cg = (const float4*)cent + (size_t)kt * BN * 32;
        #pragma unroll
        for (int p = 0; p < 8; p++) {
            int id = tid + p * 256;
            int r = id >> 5, c4 = id & 31;
            cs[r * 32 + (c4 ^ ((r >> 2) & 7))] = cg[id];
        }
        __syncthreads();

        float acc[4][4];
        #pragma unroll
        for (int i = 0; i < 4; i++)
            #pragma unroll
            for (int j = 0; j < 4; j++) acc[i][j] = 0.f;

        // strictly ascending d, single accumulator, fmaf chain (sgemm semantics)
        #pragma unroll 4
        for (int d4 = 0; d4 < 32; d4++) {
            float4 xa[4], ca[4];
            #pragma unroll
            for (int i = 0; i < 4; i++) xa[i] = xs[(ty * 4 + i) * 32 + (d4 ^ (ty & 7))];
            #pragma unroll
            for (int j = 0; j < 4; j++) ca[j] = cs[(tx * 4 + j) * 32 + (d4 ^ (tx & 7))];
            #pragma unroll
            for (int i = 0; i < 4; i++)
                #pragma unroll
                for (int j = 0; j < 4; j++) {
                    acc[i][j] = fmaf(xa[i].x, ca[j].x, acc[i][j]);
                    acc[i][j] = fmaf(xa[i].y, ca[j].y, acc[i][j]);
                    acc[i][j] = fmaf(xa[i].z, ca[j].z, acc[i][j]);
                    acc[i][j] = fmaf(xa[i].w, ca[j].w, acc[i][j]);
                }
        }

        #pragma unroll
        for (int j = 0; j < 4; j++) {
            int kk = kt * BN + tx * 4 + j;
            float cq = csq[kk];
            #pragma unroll
            for (int i = 0; i < 4; i++) {
                // fl(fl(xsq - fl(2*dot)) + csq) -- forced, no contraction
                float t = __fmul_rn(2.0f, acc[i][j]);
                float d = __fadd_rn(__fsub_rn(xq[i], t), cq);
                bool nn = (d != d);
                if ((d < best[i]) || (nn && (best[i] == best[i]))) {
                    best[i] = d; bidx[i] = kk;
                }
            }
        }
    }

    #pragma unroll
    for (int m = 1; m < 16; m <<= 1) {
        #pragma unroll
        for (int i = 0; i < 4; i++) {
            float od = __shfl_xor(best[i], m, 64);
            int oi = __shfl_xor(bidx[i], m, 64);
            bool n1 = (best[i] != best[i]), n2 = (od != od);
            bool take;
            if (n1 && n2) take = (oi < bidx[i]);
            else if (n2) take = true;
            else if (n1) take = false;
            else take = (od < best[i]) || (od == best[i] && oi < bidx[i]);
            if (take) { best[i] = od; bidx[i] = oi; }
        }
    }
    if (tx == 0) {
        #pragma unroll
        for (int i = 0; i < 4; i++) cl[bm + ty * 4 + i] = bidx[i];
    }
}

// ---- deterministic index-ordered segment sums via counting sort ----
__global__ void hist_kernel(const int* __restrict__ cl, int* __restrict__ cnt, int n) {
    int i = blockIdx.x * 256 + threadIdx.x;
    if (i < n) atomicAdd(&cnt[cl[i]], 1);
}

__global__ void scan_kernel(const int* __restrict__ cnt, int* __restrict__ off,
                            int* __restrict__ cursor) {
    __shared__ int s[KC];
    int t = threadIdx.x;
    s[t] = cnt[t];
    __syncthreads();
    for (int o = 1; o < KC; o <<= 1) {
        int v = (t >= o) ? s[t - o] : 0;
        __syncthreads();
        s[t] += v;
        __syncthreads();
    }
    int excl = s[t] - cnt[t];
    off[t] = excl;
    cursor[t] = excl;
}

__global__ void scatter_kernel(const int* __restrict__ cl, int* __restrict__ cursor,
                               int* __restrict__ list, int n) {
    int i = blockIdx.x * 256 + threadIdx.x;
    if (i < n) {
        int c = cl[i];
        int pos = atomicAdd(&cursor[c], 1);
        list[pos] = i;
    }
}

// one thread per cluster: insertion-sort its index list ascending
__global__ void sort_kernel(const int* __restrict__ off, const int* __restrict__ cnt,
                            int* __restrict__ list) {
    int k = blockIdx.x * 256 + threadIdx.x;
    if (k >= KC) return;
    int o = off[k], m = cnt[k];
    for (int a = 1; a < m; a++) {
        int key = list[o + a];
        int b = a - 1;
        while (b >= 0 && list[o + b] > key) { list[o + b + 1] = list[o + b]; b--; }
        list[o + b + 1] = key;
    }
}

// block per cluster, thread = dim: sequential fp32 adds in ascending point index
__global__ __launch_bounds__(128) void sum_kernel(
    const float* __restrict__ x, const int* __restrict__ list,
    const int* __restrict__ off, const int* __restrict__ cnt,
    float* __restrict__ cent, float* __restrict__ countsF)
{
    int k = blockIdx.x;
    int d = threadIdx.x;
    int o = off[k], m = cnt[k];
    float s = 0.f;
    for (int j = 0; j < m; j++) {
        int idx = list[o + j];
        s = __fadd_rn(s, x[(size_t)idx * DIM + d]);
    }
    cent[(size_t)k * DIM + d] = __fdiv_rn(s, (float)m);  // 0/0 -> NaN, matches ref
    if (d == 0) countsF[k] = (float)m;
}

__global__ void cl2f_kernel(const int* __restrict__ cl, float* __restrict__ out, int n) {
    int i = blockIdx.x * 256 + threadIdx.x;
    if (i < n) out[i] = (float)cl[i];
}

extern "C" void kernel_launch(void* const* d_in, const int* in_sizes, int n_in,
                              void* d_out, int out_size, void* d_ws, size_t ws_size,
                              hipStream_t stream) {
    const float* x = (const float*)d_in[0];
    const int n = in_sizes[0] / DIM;  // 131072

    // d_out: [clusters (N) | centroids (K*D) | counts (K)]
    float* clf     = (float*)d_out;
    float* cent    = clf + n;
    float* countsF = cent + KC * DIM;

    // ws scratch (~1.6 MB)
    float* xsq   = (float*)d_ws;        // N
    float* csq   = xsq + n;             // K
    int*   cl    = (int*)(csq + KC);    // N
    int*   list  = cl + n;              // N
    int*   cnt   = list + n;            // K
    int*   off   = cnt + KC;            // K
    int*   cursor= off + KC;            // K

    hipMemcpyAsync(cent, x, (size_t)KC * DIM * sizeof(float),
                   hipMemcpyDeviceToDevice, stream);
    sq_np_kernel<<<(n + 255) / 256, 256, 0, stream>>>(x, xsq, n);

    for (int it = 0; it < NITER; it++) {
        sq_np_kernel<<<(KC + 255) / 256, 256, 0, stream>>>(cent, csq, KC);
        assign_kernel<<<n / BM, 256, 0, stream>>>(x, cent, xsq, csq, cl);
        hipMemsetAsync(cnt, 0, KC * sizeof(int), stream);
        hist_kernel<<<(n + 255) / 256, 256, 0, stream>>>(cl, cnt, n);
        scan_kernel<<<1, KC, 0, stream>>>(cnt, off, cursor);
        scatter_kernel<<<(n + 255) / 256, 256, 0, stream>>>(cl, cursor, list, n);
        sort_kernel<<<(KC + 255) / 256, 256, 0, stream>>>(off, cnt, list);
        sum_kernel<<<KC, DIM, 0, stream>>>(x, list, off, cnt, cent, countsF);
    }

    cl2f_kernel<<<(n + 255) / 256, 256, 0, stream>>>(cl, clf, n);
}

// Round 7
// 7725.388 us; speedup vs baseline: 36.5320x; 36.5320x over previous
//
#include <hip/hip_runtime.h>
#include <math.h>

#define DIM 128
#define KC 1024
#define NITER 10
#define BM 64
#define BN 64
#define NB 512   // scatter blocks: n / 256

// ---- numpy-pairwise sum of squares (n=128 path), bit-exact clone ----
__global__ void sq_np_kernel(const float* __restrict__ v, float* __restrict__ out, int rows) {
    int i = blockIdx.x * blockDim.x + threadIdx.x;
    if (i >= rows) return;
    const float4* row = (const float4*)(v + (size_t)i * DIM);
    float r[8];
    {
        float4 a = row[0], b = row[1];
        r[0] = __fmul_rn(a.x, a.x); r[1] = __fmul_rn(a.y, a.y);
        r[2] = __fmul_rn(a.z, a.z); r[3] = __fmul_rn(a.w, a.w);
        r[4] = __fmul_rn(b.x, b.x); r[5] = __fmul_rn(b.y, b.y);
        r[6] = __fmul_rn(b.z, b.z); r[7] = __fmul_rn(b.w, b.w);
    }
    #pragma unroll
    for (int blk = 1; blk < 16; blk++) {
        float4 a = row[blk * 2], b = row[blk * 2 + 1];
        r[0] = __fadd_rn(r[0], __fmul_rn(a.x, a.x));
        r[1] = __fadd_rn(r[1], __fmul_rn(a.y, a.y));
        r[2] = __fadd_rn(r[2], __fmul_rn(a.z, a.z));
        r[3] = __fadd_rn(r[3], __fmul_rn(a.w, a.w));
        r[4] = __fadd_rn(r[4], __fmul_rn(b.x, b.x));
        r[5] = __fadd_rn(r[5], __fmul_rn(b.y, b.y));
        r[6] = __fadd_rn(r[6], __fmul_rn(b.z, b.z));
        r[7] = __fadd_rn(r[7], __fmul_rn(b.w, b.w));
    }
    out[i] = __fadd_rn(__fadd_rn(__fadd_rn(r[0], r[1]), __fadd_rn(r[2], r[3])),
                       __fadd_rn(__fadd_rn(r[4], r[5]), __fadd_rn(r[6], r[7])));
}

// ---- assign: fp32, sgemm-style sequential-fma dot, d=(xsq-2dot)+csq ----
// UNCHANGED from the passing R6 kernel (numerics frozen).
__global__ __launch_bounds__(256) void assign_kernel(
    const float* __restrict__ x, const float* __restrict__ cent,
    const float* __restrict__ xsq, const float* __restrict__ csq,
    int* __restrict__ cl)
{
    __shared__ float4 xs[BM * 32];
    __shared__ float4 cs[BN * 32];
    const int tid = threadIdx.x;
    const int bm = blockIdx.x * BM;

    const float4* xg = (const float4*)x + (size_t)bm * 32;
    #pragma unroll
    for (int p = 0; p < 8; p++) {
        int id = tid + p * 256;
        int r = id >> 5, c4 = id & 31;
        xs[r * 32 + (c4 ^ ((r >> 2) & 7))] = xg[id];
    }

    const int ty = tid >> 4, tx = tid & 15;
    float best[4];
    int bidx[4];
    float xq[4];
    #pragma unroll
    for (int i = 0; i < 4; i++) {
        best[i] = INFINITY; bidx[i] = 0;
        xq[i] = xsq[bm + ty * 4 + i];
    }

    for (int kt = 0; kt < KC / BN; kt++) {
        __syncthreads();
        const float4* cg = (const float4*)cent + (size_t)kt * BN * 32;
        #pragma unroll
        for (int p = 0; p < 8; p++) {
            int id = tid + p * 256;
            int r = id >> 5, c4 = id & 31;
            cs[r * 32 + (c4 ^ ((r >> 2) & 7))] = cg[id];
        }
        __syncthreads();

        float acc[4][4];
        #pragma unroll
        for (int i = 0; i < 4; i++)
            #pragma unroll
            for (int j = 0; j < 4; j++) acc[i][j] = 0.f;

        #pragma unroll 4
        for (int d4 = 0; d4 < 32; d4++) {
            float4 xa[4], ca[4];
            #pragma unroll
            for (int i = 0; i < 4; i++) xa[i] = xs[(ty * 4 + i) * 32 + (d4 ^ (ty & 7))];
            #pragma unroll
            for (int j = 0; j < 4; j++) ca[j] = cs[(tx * 4 + j) * 32 + (d4 ^ (tx & 7))];
            #pragma unroll
            for (int i = 0; i < 4; i++)
                #pragma unroll
                for (int j = 0; j < 4; j++) {
                    acc[i][j] = fmaf(xa[i].x, ca[j].x, acc[i][j]);
                    acc[i][j] = fmaf(xa[i].y, ca[j].y, acc[i][j]);
                    acc[i][j] = fmaf(xa[i].z, ca[j].z, acc[i][j]);
                    acc[i][j] = fmaf(xa[i].w, ca[j].w, acc[i][j]);
                }
        }

        #pragma unroll
        for (int j = 0; j < 4; j++) {
            int kk = kt * BN + tx * 4 + j;
            float cq = csq[kk];
            #pragma unroll
            for (int i = 0; i < 4; i++) {
                float t = __fmul_rn(2.0f, acc[i][j]);
                float d = __fadd_rn(__fsub_rn(xq[i], t), cq);
                bool nn = (d != d);
                if ((d < best[i]) || (nn && (best[i] == best[i]))) {
                    best[i] = d; bidx[i] = kk;
                }
            }
        }
    }

    #pragma unroll
    for (int m = 1; m < 16; m <<= 1) {
        #pragma unroll
        for (int i = 0; i < 4; i++) {
            float od = __shfl_xor(best[i], m, 64);
            int oi = __shfl_xor(bidx[i], m, 64);
            bool n1 = (best[i] != best[i]), n2 = (od != od);
            bool take;
            if (n1 && n2) take = (oi < bidx[i]);
            else if (n2) take = true;
            else if (n1) take = false;
            else take = (od < best[i]) || (od == best[i] && oi < bidx[i]);
            if (take) { best[i] = od; bidx[i] = oi; }
        }
    }
    if (tx == 0) {
        #pragma unroll
        for (int i = 0; i < 4; i++) cl[bm + ty * 4 + i] = bidx[i];
    }
}

// ---- stable counting-scatter (replaces O(m^2) insertion sort) ----
// Produces list[] bit-identical to "per-cluster ascending point index".

// per-block histogram: block b covers points [b*256, b*256+256)
__global__ __launch_bounds__(256) void bhist_kernel(const int* __restrict__ cl,
                                                    int* __restrict__ bhist, int n) {
    __shared__ int h[KC];
    int t = threadIdx.x;
    #pragma unroll
    for (int q = 0; q < KC / 256; q++) h[t + q * 256] = 0;
    __syncthreads();
    int i = blockIdx.x * 256 + t;
    if (i < n) atomicAdd(&h[cl[i]], 1);
    __syncthreads();
    int* row = bhist + (size_t)blockIdx.x * KC;
    #pragma unroll
    for (int q = 0; q < KC / 256; q++) row[t + q * 256] = h[t + q * 256];
}

// per-cluster totals: thread k sums its column over all blocks
__global__ __launch_bounds__(256) void colsum_kernel(const int* __restrict__ bhist,
                                                     int* __restrict__ cnt) {
    int k = blockIdx.x * 256 + threadIdx.x;
    int s = 0;
    for (int b = 0; b < NB; b++) s += bhist[(size_t)b * KC + k];
    cnt[k] = s;
}

// exclusive scan over clusters -> off[k]
__global__ void scan_kernel(const int* __restrict__ cnt, int* __restrict__ off) {
    __shared__ int s[KC];
    int t = threadIdx.x;
    s[t] = cnt[t];
    __syncthreads();
    for (int o = 1; o < KC; o <<= 1) {
        int v = (t >= o) ? s[t - o] : 0;
        __syncthreads();
        s[t] += v;
        __syncthreads();
    }
    off[t] = s[t] - cnt[t];
}

// per-cluster prefix over blocks: bhist[b][k] <- off[k] + sum_{b'<b} hist[b'][k]
__global__ __launch_bounds__(256) void blockpfx_kernel(int* __restrict__ bhist,
                                                       const int* __restrict__ off) {
    int k = blockIdx.x * 256 + threadIdx.x;
    int run = off[k];
    for (int b = 0; b < NB; b++) {
        size_t idx = (size_t)b * KC + k;
        int t = bhist[idx];
        bhist[idx] = run;
        run += t;
    }
}

// stable scatter: intra-block rank in point-index order, then place
__global__ __launch_bounds__(256) void stable_scatter_kernel(
    const int* __restrict__ cl, const int* __restrict__ bhist,
    int* __restrict__ list, int n)
{
    __shared__ int cls[256];
    int t = threadIdx.x;
    int i = blockIdx.x * 256 + t;
    int c = (i < n) ? cl[i] : -1;
    cls[t] = c;
    __syncthreads();
    if (i >= n) return;
    int rank = 0;
    for (int j = 0; j < 256; j++)
        rank += (j < t && cls[j] == c) ? 1 : 0;
    list[bhist[(size_t)blockIdx.x * KC + c] + rank] = i;
}

// block per cluster, thread = dim: sequential fp32 adds in ascending point index
__global__ __launch_bounds__(128) void sum_kernel(
    const float* __restrict__ x, const int* __restrict__ list,
    const int* __restrict__ off, const int* __restrict__ cnt,
    float* __restrict__ cent, float* __restrict__ countsF)
{
    int k = blockIdx.x;
    int d = threadIdx.x;
    int o = off[k], m = cnt[k];
    float s = 0.f;
    for (int j = 0; j < m; j++) {
        int idx = list[o + j];
        s = __fadd_rn(s, x[(size_t)idx * DIM + d]);
    }
    cent[(size_t)k * DIM + d] = __fdiv_rn(s, (float)m);  // 0/0 -> NaN, matches ref
    if (d == 0) countsF[k] = (float)m;
}

__global__ void cl2f_kernel(const int* __restrict__ cl, float* __restrict__ out, int n) {
    int i = blockIdx.x * 256 + threadIdx.x;
    if (i < n) out[i] = (float)cl[i];
}

extern "C" void kernel_launch(void* const* d_in, const int* in_sizes, int n_in,
                              void* d_out, int out_size, void* d_ws, size_t ws_size,
                              hipStream_t stream) {
    const float* x = (const float*)d_in[0];
    const int n = in_sizes[0] / DIM;  // 131072

    // d_out: [clusters (N) | centroids (K*D) | counts (K)]
    float* clf     = (float*)d_out;
    float* cent    = clf + n;
    float* countsF = cent + KC * DIM;

    // ws scratch (~3.6 MB) — R3 (3.7 MB) and R5 (0 B) gave identical outputs,
    // so ws at this size is not aliased.
    float* xsq   = (float*)d_ws;          // N
    float* csq   = xsq + n;               // K
    int*   cl    = (int*)(csq + KC);      // N
    int*   list  = cl + n;                // N
    int*   cnt   = list + n;              // K
    int*   off   = cnt + KC;              // K
    int*   bhist = off + KC;              // NB*K  (2 MB)

    hipMemcpyAsync(cent, x, (size_t)KC * DIM * sizeof(float),
                   hipMemcpyDeviceToDevice, stream);
    sq_np_kernel<<<(n + 255) / 256, 256, 0, stream>>>(x, xsq, n);

    for (int it = 0; it < NITER; it++) {
        sq_np_kernel<<<(KC + 255) / 256, 256, 0, stream>>>(cent, csq, KC);
        assign_kernel<<<n / BM, 256, 0, stream>>>(x, cent, xsq, csq, cl);
        bhist_kernel<<<NB, 256, 0, stream>>>(cl, bhist, n);
        colsum_kernel<<<KC / 256, 256, 0, stream>>>(bhist, cnt);
        scan_kernel<<<1, KC, 0, stream>>>(cnt, off);
        blockpfx_kernel<<<KC / 256, 256, 0, stream>>>(bhist, off);
        stable_scatter_kernel<<<NB, 256, 0, stream>>>(cl, bhist, list, n);
        sum_kernel<<<KC, DIM, 0, stream>>>(x, list, off, cnt, cent, countsF);
    }

    cl2f_kernel<<<(n + 255) / 256, 256, 0, stream>>>(cl, clf, n);
}

// Round 8
// 6333.143 us; speedup vs baseline: 44.5630x; 1.2198x over previous
//
#include <hip/hip_runtime.h>
#include <math.h>

#define DIM 128
#define KC 1024
#define NITER 10
#define BM 64
#define BN 64
#define NB 512   // scatter blocks: n / 256

// ---- numpy-pairwise sum of squares (n=128 path), bit-exact clone ----
__global__ void sq_np_kernel(const float* __restrict__ v, float* __restrict__ out, int rows) {
    int i = blockIdx.x * blockDim.x + threadIdx.x;
    if (i >= rows) return;
    const float4* row = (const float4*)(v + (size_t)i * DIM);
    float r[8];
    {
        float4 a = row[0], b = row[1];
        r[0] = __fmul_rn(a.x, a.x); r[1] = __fmul_rn(a.y, a.y);
        r[2] = __fmul_rn(a.z, a.z); r[3] = __fmul_rn(a.w, a.w);
        r[4] = __fmul_rn(b.x, b.x); r[5] = __fmul_rn(b.y, b.y);
        r[6] = __fmul_rn(b.z, b.z); r[7] = __fmul_rn(b.w, b.w);
    }
    #pragma unroll
    for (int blk = 1; blk < 16; blk++) {
        float4 a = row[blk * 2], b = row[blk * 2 + 1];
        r[0] = __fadd_rn(r[0], __fmul_rn(a.x, a.x));
        r[1] = __fadd_rn(r[1], __fmul_rn(a.y, a.y));
        r[2] = __fadd_rn(r[2], __fmul_rn(a.z, a.z));
        r[3] = __fadd_rn(r[3], __fmul_rn(a.w, a.w));
        r[4] = __fadd_rn(r[4], __fmul_rn(b.x, b.x));
        r[5] = __fadd_rn(r[5], __fmul_rn(b.y, b.y));
        r[6] = __fadd_rn(r[6], __fmul_rn(b.z, b.z));
        r[7] = __fadd_rn(r[7], __fmul_rn(b.w, b.w));
    }
    out[i] = __fadd_rn(__fadd_rn(__fadd_rn(r[0], r[1]), __fadd_rn(r[2], r[3])),
                       __fadd_rn(__fadd_rn(r[4], r[5]), __fadd_rn(r[6], r[7])));
}

// ---- assign: fp32, sgemm-style sequential-fma dot, d=(xsq-2dot)+csq ----
// UNCHANGED (numerics frozen since the R6 pass).
__global__ __launch_bounds__(256) void assign_kernel(
    const float* __restrict__ x, const float* __restrict__ cent,
    const float* __restrict__ xsq, const float* __restrict__ csq,
    int* __restrict__ cl)
{
    __shared__ float4 xs[BM * 32];
    __shared__ float4 cs[BN * 32];
    const int tid = threadIdx.x;
    const int bm = blockIdx.x * BM;

    const float4* xg = (const float4*)x + (size_t)bm * 32;
    #pragma unroll
    for (int p = 0; p < 8; p++) {
        int id = tid + p * 256;
        int r = id >> 5, c4 = id & 31;
        xs[r * 32 + (c4 ^ ((r >> 2) & 7))] = xg[id];
    }

    const int ty = tid >> 4, tx = tid & 15;
    float best[4];
    int bidx[4];
    float xq[4];
    #pragma unroll
    for (int i = 0; i < 4; i++) {
        best[i] = INFINITY; bidx[i] = 0;
        xq[i] = xsq[bm + ty * 4 + i];
    }

    for (int kt = 0; kt < KC / BN; kt++) {
        __syncthreads();
        const float4* cg = (const float4*)cent + (size_t)kt * BN * 32;
        #pragma unroll
        for (int p = 0; p < 8; p++) {
            int id = tid + p * 256;
            int r = id >> 5, c4 = id & 31;
            cs[r * 32 + (c4 ^ ((r >> 2) & 7))] = cg[id];
        }
        __syncthreads();

        float acc[4][4];
        #pragma unroll
        for (int i = 0; i < 4; i++)
            #pragma unroll
            for (int j = 0; j < 4; j++) acc[i][j] = 0.f;

        #pragma unroll 4
        for (int d4 = 0; d4 < 32; d4++) {
            float4 xa[4], ca[4];
            #pragma unroll
            for (int i = 0; i < 4; i++) xa[i] = xs[(ty * 4 + i) * 32 + (d4 ^ (ty & 7))];
            #pragma unroll
            for (int j = 0; j < 4; j++) ca[j] = cs[(tx * 4 + j) * 32 + (d4 ^ (tx & 7))];
            #pragma unroll
            for (int i = 0; i < 4; i++)
                #pragma unroll
                for (int j = 0; j < 4; j++) {
                    acc[i][j] = fmaf(xa[i].x, ca[j].x, acc[i][j]);
                    acc[i][j] = fmaf(xa[i].y, ca[j].y, acc[i][j]);
                    acc[i][j] = fmaf(xa[i].z, ca[j].z, acc[i][j]);
                    acc[i][j] = fmaf(xa[i].w, ca[j].w, acc[i][j]);
                }
        }

        #pragma unroll
        for (int j = 0; j < 4; j++) {
            int kk = kt * BN + tx * 4 + j;
            float cq = csq[kk];
            #pragma unroll
            for (int i = 0; i < 4; i++) {
                float t = __fmul_rn(2.0f, acc[i][j]);
                float d = __fadd_rn(__fsub_rn(xq[i], t), cq);
                bool nn = (d != d);
                if ((d < best[i]) || (nn && (best[i] == best[i]))) {
                    best[i] = d; bidx[i] = kk;
                }
            }
        }
    }

    #pragma unroll
    for (int m = 1; m < 16; m <<= 1) {
        #pragma unroll
        for (int i = 0; i < 4; i++) {
            float od = __shfl_xor(best[i], m, 64);
            int oi = __shfl_xor(bidx[i], m, 64);
            bool n1 = (best[i] != best[i]), n2 = (od != od);
            bool take;
            if (n1 && n2) take = (oi < bidx[i]);
            else if (n2) take = true;
            else if (n1) take = false;
            else take = (od < best[i]) || (od == best[i] && oi < bidx[i]);
            if (take) { best[i] = od; bidx[i] = oi; }
        }
    }
    if (tx == 0) {
        #pragma unroll
        for (int i = 0; i < 4; i++) cl[bm + ty * 4 + i] = bidx[i];
    }
}

// ---- stable counting-scatter: list[] = per-cluster ascending point index ----

__global__ __launch_bounds__(256) void bhist_kernel(const int* __restrict__ cl,
                                                    int* __restrict__ bhist, int n) {
    __shared__ int h[KC];
    int t = threadIdx.x;
    #pragma unroll
    for (int q = 0; q < KC / 256; q++) h[t + q * 256] = 0;
    __syncthreads();
    int i = blockIdx.x * 256 + t;
    if (i < n) atomicAdd(&h[cl[i]], 1);
    __syncthreads();
    int* row = bhist + (size_t)blockIdx.x * KC;
    #pragma unroll
    for (int q = 0; q < KC / 256; q++) row[t + q * 256] = h[t + q * 256];
}

__global__ __launch_bounds__(256) void colsum_kernel(const int* __restrict__ bhist,
                                                     int* __restrict__ cnt) {
    int k = blockIdx.x * 256 + threadIdx.x;
    int s = 0;
    for (int b = 0; b < NB; b++) s += bhist[(size_t)b * KC + k];
    cnt[k] = s;
}

__global__ void scan_kernel(const int* __restrict__ cnt, int* __restrict__ off) {
    __shared__ int s[KC];
    int t = threadIdx.x;
    s[t] = cnt[t];
    __syncthreads();
    for (int o = 1; o < KC; o <<= 1) {
        int v = (t >= o) ? s[t - o] : 0;
        __syncthreads();
        s[t] += v;
        __syncthreads();
    }
    off[t] = s[t] - cnt[t];
}

__global__ __launch_bounds__(256) void blockpfx_kernel(int* __restrict__ bhist,
                                                       const int* __restrict__ off) {
    int k = blockIdx.x * 256 + threadIdx.x;
    int run = off[k];
    for (int b = 0; b < NB; b++) {
        size_t idx = (size_t)b * KC + k;
        int t = bhist[idx];
        bhist[idx] = run;
        run += t;
    }
}

__global__ __launch_bounds__(256) void stable_scatter_kernel(
    const int* __restrict__ cl, const int* __restrict__ bhist,
    int* __restrict__ list, int n)
{
    __shared__ int cls[256];
    int t = threadIdx.x;
    int i = blockIdx.x * 256 + t;
    int c = (i < n) ? cl[i] : -1;
    cls[t] = c;
    __syncthreads();
    if (i >= n) return;
    int rank = 0;
    for (int j = 0; j < 256; j++)
        rank += (j < t && cls[j] == c) ? 1 : 0;
    list[bhist[(size_t)blockIdx.x * KC + c] + rank] = i;
}

// ---- segment sum, same bitwise add order, latency-hidden ----
// Loads are accumulator-independent: stage 512 indices in LDS, issue 16
// independent row-loads per group, THEN do the sequential __fadd_rn chain
// (order identical to R7's passing kernel -> trajectory bit-identical).
#define CHUNK 512
__global__ __launch_bounds__(128) void sum_kernel(
    const float* __restrict__ x, const int* __restrict__ list,
    const int* __restrict__ off, const int* __restrict__ cnt,
    float* __restrict__ cent, float* __restrict__ countsF)
{
    __shared__ int sidx[CHUNK];
    int k = blockIdx.x;
    int d = threadIdx.x;
    int o = off[k], m = cnt[k];
    float s = 0.f;
    for (int base = 0; base < m; base += CHUNK) {
        int c = m - base; if (c > CHUNK) c = CHUNK;
        __syncthreads();
        for (int t = d; t < c; t += 128) sidx[t] = list[o + base + t];
        __syncthreads();
        int j = 0;
        for (; j + 16 <= c; j += 16) {
            float v[16];
            #pragma unroll
            for (int u = 0; u < 16; u++)
                v[u] = x[(size_t)sidx[j + u] * DIM + d];
            #pragma unroll
            for (int u = 0; u < 16; u++)
                s = __fadd_rn(s, v[u]);
        }
        for (; j < c; j++)
            s = __fadd_rn(s, x[(size_t)sidx[j] * DIM + d]);
    }
    cent[(size_t)k * DIM + d] = __fdiv_rn(s, (float)m);  // 0/0 -> NaN, matches ref
    if (d == 0) countsF[k] = (float)m;
}

__global__ void cl2f_kernel(const int* __restrict__ cl, float* __restrict__ out, int n) {
    int i = blockIdx.x * 256 + threadIdx.x;
    if (i < n) out[i] = (float)cl[i];
}

extern "C" void kernel_launch(void* const* d_in, const int* in_sizes, int n_in,
                              void* d_out, int out_size, void* d_ws, size_t ws_size,
                              hipStream_t stream) {
    const float* x = (const float*)d_in[0];
    const int n = in_sizes[0] / DIM;  // 131072

    // d_out: [clusters (N) | centroids (K*D) | counts (K)]
    float* clf     = (float*)d_out;
    float* cent    = clf + n;
    float* countsF = cent + KC * DIM;

    // ws scratch (~3.6 MB)
    float* xsq   = (float*)d_ws;          // N
    float* csq   = xsq + n;               // K
    int*   cl    = (int*)(csq + KC);      // N
    int*   list  = cl + n;                // N
    int*   cnt   = list + n;              // K
    int*   off   = cnt + KC;              // K
    int*   bhist = off + KC;              // NB*K  (2 MB)

    hipMemcpyAsync(cent, x, (size_t)KC * DIM * sizeof(float),
                   hipMemcpyDeviceToDevice, stream);
    sq_np_kernel<<<(n + 255) / 256, 256, 0, stream>>>(x, xsq, n);

    for (int it = 0; it < NITER; it++) {
        sq_np_kernel<<<(KC + 255) / 256, 256, 0, stream>>>(cent, csq, KC);
        assign_kernel<<<n / BM, 256, 0, stream>>>(x, cent, xsq, csq, cl);
        bhist_kernel<<<NB, 256, 0, stream>>>(cl, bhist, n);
        colsum_kernel<<<KC / 256, 256, 0, stream>>>(bhist, cnt);
        scan_kernel<<<1, KC, 0, stream>>>(cnt, off);
        blockpfx_kernel<<<KC / 256, 256, 0, stream>>>(bhist, off);
        stable_scatter_kernel<<<NB, 256, 0, stream>>>(cl, bhist, list, n);
        sum_kernel<<<KC, DIM, 0, stream>>>(x, list, off, cnt, cent, countsF);
    }

    cl2f_kernel<<<(n + 255) / 256, 256, 0, stream>>>(cl, clf, n);
}